// Round 1
// baseline (5071.352 us; speedup 1.0000x reference)
//
#include <hip/hip_runtime.h>
#include <math.h>

// InformationPlane: per 512-batch -> pdist2 GEMMs, sigma search, RBF Grams,
// 5x symmetric 512x512 eigvalsh (Jacobi w/ early exit), Renyi entropies, MI.
// d_out[0..NTOT) = x copy; d_out[NTOT]=Ixt_mean, d_out[NTOT+1]=Ity_mean.
// First 42MB of d_out double as matrix scratch before the final x copy.

#define NBATCH 8
#define MBS    512
#define DXX    8192
#define DII    3072
#define NSIG   50
#define NN     262144                 // 512*512
#define NTOT   ((size_t)33554432)     // 4096*8192

// scal (double) indices
#define I_SUMD  0    // 8
#define I_KYF   8    // 8
#define I_MEAND 16   // 8
#define I_SIGMA 24   // 8
#define I_ENT   32   // 40 (b*5+m)
#define I_NUM   96   // 8*50
#define I_DEN   512  // 8*50 -> ends 912

__device__ __forceinline__ size_t slotOf(int b, int m) {
  return ((size_t)(b * 5 + m)) * (size_t)NN;
}

// ---------------- copy x -> out ----------------
__global__ void k_copy(const float4* __restrict__ src, float4* __restrict__ dst, size_t n4) {
  size_t i = (size_t)blockIdx.x * blockDim.x + threadIdx.x;
  size_t stride = (size_t)gridDim.x * blockDim.x;
  for (; i < n4; i += stride) dst[i] = src[i];
}

// ---------------- row squared norms ----------------
__global__ void k_rownorm(const float* __restrict__ src, int D, float* __restrict__ out) {
  int row = blockIdx.x;
  const float* p = src + (size_t)row * D;
  double s = 0.0;
  for (int c = threadIdx.x; c < D; c += 256) { float v = p[c]; s += (double)v * v; }
  __shared__ double red[256];
  red[threadIdx.x] = s; __syncthreads();
  for (int o = 128; o > 0; o >>= 1) {
    if (threadIdx.x < o) red[threadIdx.x] += red[threadIdx.x + o];
    __syncthreads();
  }
  if (threadIdx.x == 0) out[row] = (float)red[0];
}

// ---------------- label kernel Ky (-> Ay slot), ||Ky||_F^2 ----------------
__global__ void k_ky(const float* __restrict__ lab, float* __restrict__ eig, double* __restrict__ scal) {
  int b = blockIdx.y;
  int e = blockIdx.x * 256 + threadIdx.x;   // 0..NN-1 (grid.x = 1024)
  int i = e >> 9, j = e & 511;
  const float* L = lab + (size_t)b * MBS * 10;
  float d2 = 0.0f;
#pragma unroll
  for (int d = 0; d < 10; d++) { float t = L[i * 10 + d] - L[j * 10 + d]; d2 += t * t; }
  float ky = __expf(-d2 * 100.0f);          // sigma = 0.1 -> /0.01
  eig[slotOf(b, 2) + e] = ky * (1.0f / 512.0f);   // Ay = Ky/n
  __shared__ double red[256];
  red[threadIdx.x] = (double)ky * ky; __syncthreads();
  for (int o = 128; o > 0; o >>= 1) {
    if (threadIdx.x < o) red[threadIdx.x] += red[threadIdx.x + o];
    __syncthreads();
  }
  if (threadIdx.x == 0) atomicAdd(&scal[I_KYF + b], red[0]);
}

// ---------------- pdist2 GEMM + epilogue ----------------
// MODE 0: x -> writes d2 into slot(b,1), fused sum(sqrt(d2)) & count(d2>0)
// MODE 1: input -> writes Ax = exp(-d2/64)/512 into slot(b,0)
template <int D, int MODE>
__global__ void k_gemm(const float* __restrict__ X, const float* __restrict__ nrm,
                       float* __restrict__ eig, double* __restrict__ scal,
                       unsigned long long* __restrict__ cnt) {
  int b = blockIdx.z;
  const float* Xb = X + (size_t)b * MBS * D;
  const float* nb = nrm + b * MBS;
  __shared__ float As[64][33];
  __shared__ float Bs[64][33];
  int tx = threadIdx.x, ty = threadIdx.y;
  int tid = ty * 16 + tx;
  int row0 = blockIdx.x * 64, col0 = blockIdx.y * 64;
  float acc[4][4] = {};
  for (int k0 = 0; k0 < D; k0 += 32) {
#pragma unroll
    for (int l = 0; l < 8; l++) {
      int idx = tid + l * 256; int r = idx >> 5, c = idx & 31;
      As[r][c] = Xb[(size_t)(row0 + r) * D + k0 + c];
      Bs[r][c] = Xb[(size_t)(col0 + r) * D + k0 + c];
    }
    __syncthreads();
#pragma unroll
    for (int kk = 0; kk < 32; kk++) {
      float a[4], bb[4];
#pragma unroll
      for (int i = 0; i < 4; i++) { a[i] = As[ty * 4 + i][kk]; bb[i] = Bs[tx * 4 + i][kk]; }
#pragma unroll
      for (int i = 0; i < 4; i++)
#pragma unroll
        for (int j = 0; j < 4; j++) acc[i][j] += a[i] * bb[j];
    }
    __syncthreads();
  }
  float* dst = eig + slotOf(b, (MODE == 0) ? 1 : 0);
  double lsum = 0.0; unsigned lcnt = 0;
#pragma unroll
  for (int i = 0; i < 4; i++) {
    int gi = row0 + ty * 4 + i;
#pragma unroll
    for (int j = 0; j < 4; j++) {
      int gj = col0 + tx * 4 + j;
      float d2 = nb[gi] + nb[gj] - 2.0f * acc[i][j];
      d2 = fmaxf(d2, 0.0f);
      if (gi == gj) d2 = 0.0f;     // force exact-zero diagonal
      if (MODE == 0) {
        dst[(size_t)gi * MBS + gj] = d2;
        if (d2 > 0.0f) { lsum += sqrt((double)d2); lcnt++; }
      } else {
        dst[(size_t)gi * MBS + gj] = __expf(-d2 * (1.0f / 64.0f)) * (1.0f / 512.0f);
      }
    }
  }
  if (MODE == 0) {
    __shared__ double redd[256];
    __shared__ unsigned redi[256];
    redd[tid] = lsum; redi[tid] = lcnt; __syncthreads();
    for (int o = 128; o > 0; o >>= 1) {
      if (tid < o) { redd[tid] += redd[tid + o]; redi[tid] += redi[tid + o]; }
      __syncthreads();
    }
    if (tid == 0) {
      atomicAdd(&scal[I_SUMD + b], redd[0]);
      atomicAdd(&cnt[b], (unsigned long long)redi[0]);
    }
  }
}

// ---------------- mean_d ----------------
__global__ void k_meand(double* __restrict__ scal, const unsigned long long* __restrict__ cnt) {
  int b = threadIdx.x;
  if (b < NBATCH) {
    double c = (double)cnt[b]; if (c < 1.0) c = 1.0;
    scal[I_MEAND + b] = scal[I_SUMD + b] / c;
  }
}

// ---------------- sigma-search sums ----------------
__global__ void k_loss(const float* __restrict__ eig, double* __restrict__ scal) {
  int b = blockIdx.z, s = blockIdx.y;
  float md = (float)scal[I_MEAND + b];
  float sg = md * (0.1f + 0.198f * (float)s);
  float inv = 1.0f / (sg * sg);
  const float* d2p = eig + slotOf(b, 1);
  const float* ayp = eig + slotOf(b, 2);
  size_t base = (size_t)blockIdx.x * 8192 + threadIdx.x;
  double ln = 0.0, ld = 0.0;
  for (int l = 0; l < 32; l++) {
    size_t e = base + (size_t)l * 256;
    float d2 = d2p[e];
    float ky = ayp[e] * 512.0f;
    float k = __expf(-d2 * inv);
    ln += (double)k * ky;
    ld += (double)k * k;
  }
  __shared__ double rn[256], rd[256];
  rn[threadIdx.x] = ln; rd[threadIdx.x] = ld; __syncthreads();
  for (int o = 128; o > 0; o >>= 1) {
    if (threadIdx.x < o) { rn[threadIdx.x] += rn[threadIdx.x + o]; rd[threadIdx.x] += rd[threadIdx.x + o]; }
    __syncthreads();
  }
  if (threadIdx.x == 0) {
    atomicAdd(&scal[I_NUM + b * NSIG + s], rn[0]);
    atomicAdd(&scal[I_DEN + b * NSIG + s], rd[0]);
  }
}

// ---------------- argmax + EMA sigma chain ----------------
__global__ void k_sigma(double* __restrict__ scal) {
  if (threadIdx.x == 0) {
    double sigma = 0.0;
    for (int b = 0; b < NBATCH; b++) {
      double kyf = sqrt(scal[I_KYF + b]);
      double best = -1.0; int bi = 0;
      for (int s = 0; s < NSIG; s++) {
        double num = scal[I_NUM + b * NSIG + s];
        double den = sqrt(scal[I_DEN + b * NSIG + s]) * kyf;
        double loss = num / den;
        if (loss > best) { best = loss; bi = s; }
      }
      double md = scal[I_MEAND + b];
      double st = md * (0.1 + 0.198 * (double)bi);
      sigma = (b == 0) ? st : 0.5 * sigma + 0.5 * st;
      scal[I_SIGMA + b] = sigma;
    }
  }
}

// ---------------- A = exp(-d2/sigma^2)/n, in place over slot(b,1) ----------------
__global__ void k_abuild(float* __restrict__ eig, const double* __restrict__ scal) {
  int b = blockIdx.y;
  float sg = (float)scal[I_SIGMA + b];
  float inv = 1.0f / (sg * sg);
  size_t e = (size_t)blockIdx.x * 256 + threadIdx.x;
  float* A = eig + slotOf(b, 1);
  A[e] = __expf(-A[e] * inv) * (1.0f / 512.0f);
}

// ---------------- Schur products ----------------
__global__ void k_joints(float* __restrict__ eig) {
  int b = blockIdx.y;
  size_t e = (size_t)blockIdx.x * 256 + threadIdx.x;
  float ax = eig[slotOf(b, 0) + e];
  float a  = eig[slotOf(b, 1) + e];
  float ay = eig[slotOf(b, 2) + e];
  eig[slotOf(b, 3) + e] = ax * a;
  eig[slotOf(b, 4) + e] = a * ay;
}

// ---------------- symmetric eigenvalues (threshold Jacobi) + entropy ----------------
__global__ __launch_bounds__(512) void k_eigen(float* __restrict__ eig, double* __restrict__ scal) {
  int blk = blockIdx.x; int b = blk / 5, m = blk % 5;
  float* M = eig + slotOf(b, m);
  int t = threadIdx.x;
  __shared__ double red[512];
  __shared__ float csA[256], csB[256];
  __shared__ int anyrot;
  __shared__ double sh_scale, sh_off2;

  // trace (of raw matrix; Jacobi preserves it)
  red[t] = (double)M[(size_t)t * 513]; __syncthreads();
  for (int o = 256; o > 0; o >>= 1) { if (t < o) red[t] += red[t + o]; __syncthreads(); }
  if (t == 0) { double trace = red[0]; sh_scale = (m >= 3) ? 1.0 / trace : 1.0; }
  __syncthreads();
  double scale = sh_scale;

  for (int sweep = 0; sweep < 30; sweep++) {
    // off-diagonal Frobenius^2 (column-wise, coalesced)
    double s2 = 0.0;
    for (int i = 0; i < 512; i++) {
      if (i != t) { float v = M[(size_t)i * 512 + t]; s2 += (double)v * v; }
    }
    red[t] = s2; __syncthreads();
    for (int o = 256; o > 0; o >>= 1) { if (t < o) red[t] += red[t + o]; __syncthreads(); }
    if (t == 0) sh_off2 = red[0];
    __syncthreads();
    if (sh_off2 * scale * scale <= 1e-11) break;   // entropy error <= ~2e-3

    for (int r = 0; r < 511; r++) {
      if (t == 0) anyrot = 0;
      __syncthreads();
      if (t < 256) {
        int p, q;
        if (t == 0) { p = 511; q = r; }
        else { p = (r + t) % 511; q = (r + 511 - t) % 511; }
        float app = M[(size_t)p * 512 + p];
        float aqq = M[(size_t)q * 512 + q];
        float apq = M[(size_t)p * 512 + q];
        float c = 1.0f, sr = 0.0f;
        if (fabsf(apq) > 1e-12f) {
          float th = (aqq - app) / (2.0f * apq);
          float tt = ((th >= 0.0f) ? 1.0f : -1.0f) / (fabsf(th) + sqrtf(1.0f + th * th));
          c = 1.0f / sqrtf(1.0f + tt * tt);
          sr = tt * c;
          anyrot = 1;
        }
        csA[t] = c; csB[t] = sr;
      }
      __syncthreads();
      if (anyrot) {
        int pair = t >> 1, half = t & 1;
        float c = csA[pair], sr = csB[pair];
        int p, q;
        if (pair == 0) { p = 511; q = r; }
        else { p = (r + pair) % 511; q = (r + 511 - pair) % 511; }
        if (sr != 0.0f) {   // rows: J^T A
          size_t rp = (size_t)p * 512, rq = (size_t)q * 512;
          int j0 = half * 256;
          for (int j = j0; j < j0 + 256; j++) {
            float xx = M[rp + j], yy = M[rq + j];
            M[rp + j] = c * xx - sr * yy;
            M[rq + j] = sr * xx + c * yy;
          }
        }
        __syncthreads();
        if (sr != 0.0f) {   // cols: (J^T A) J
          int j0 = half * 256;
          for (int j = j0; j < j0 + 256; j++) {
            float xx = M[(size_t)j * 512 + p], yy = M[(size_t)j * 512 + q];
            M[(size_t)j * 512 + p] = c * xx - sr * yy;
            M[(size_t)j * 512 + q] = sr * xx + c * yy;
          }
        }
      }
      __syncthreads();
    }
  }

  // entropy from (near-)diagonal
  double w = (double)M[(size_t)t * 513] * scale + 1e-6;
  red[t] = -w * log2(w); __syncthreads();
  for (int o = 256; o > 0; o >>= 1) { if (t < o) red[t] += red[t + o]; __syncthreads(); }
  if (t == 0) scal[I_ENT + b * 5 + m] = red[0];
}

// ---------------- finalize MI means ----------------
__global__ void k_final(const double* __restrict__ scal, float* __restrict__ out) {
  if (threadIdx.x == 0) {
    double ixt = 0.0, ity = 0.0;
    for (int b = 0; b < NBATCH; b++) {
      const double* E = &scal[I_ENT + b * 5];
      ixt += E[0] + E[1] - E[3];
      ity += E[1] + E[2] - E[4];
    }
    out[NTOT]     = (float)(ixt / 8.0);
    out[NTOT + 1] = (float)(ity / 8.0);
  }
}

extern "C" void kernel_launch(void* const* d_in, const int* in_sizes, int n_in,
                              void* d_out, int out_size, void* d_ws, size_t ws_size,
                              hipStream_t stream) {
  const float* x   = (const float*)d_in[0];
  const float* inp = (const float*)d_in[1];
  const float* lab = (const float*)d_in[2];
  float* out = (float*)d_out;

  // Matrix scratch lives in d_out (first 42MB of the 134MB x-region);
  // the x copy happens last. d_ws only holds small scalars/norms.
  float* eig = (float*)d_out;
  char* ws = (char*)d_ws;
  double* scal = (double*)ws;                                  // 8 KB
  unsigned long long* cnt = (unsigned long long*)(ws + 8192);  // 64 B
  float* nrmx = (float*)(ws + 8192 + 256);                     // 16 KB
  float* nrmi = nrmx + 4096;                                   // 12 KB used of 16

  hipMemsetAsync(ws, 0, 8192 + 256, stream);

  k_rownorm<<<4096, 256, 0, stream>>>(x,   DXX, nrmx);
  k_rownorm<<<4096, 256, 0, stream>>>(inp, DII, nrmi);
  k_ky<<<dim3(1024, NBATCH), 256, 0, stream>>>(lab, eig, scal);
  k_gemm<DXX, 0><<<dim3(8, 8, NBATCH), dim3(16, 16), 0, stream>>>(x,   nrmx, eig, scal, cnt);
  k_gemm<DII, 1><<<dim3(8, 8, NBATCH), dim3(16, 16), 0, stream>>>(inp, nrmi, eig, scal, cnt);
  k_meand<<<1, 64, 0, stream>>>(scal, cnt);
  k_loss<<<dim3(32, NSIG, NBATCH), 256, 0, stream>>>(eig, scal);
  k_sigma<<<1, 64, 0, stream>>>(scal);
  k_abuild<<<dim3(1024, NBATCH), 256, 0, stream>>>(eig, scal);
  k_joints<<<dim3(1024, NBATCH), 256, 0, stream>>>(eig);
  k_eigen<<<40, 512, 0, stream>>>(eig, scal);
  k_final<<<1, 64, 0, stream>>>(scal, out);
  // x copy LAST (overwrites the matrix scratch region)
  k_copy<<<2048, 256, 0, stream>>>((const float4*)x, (float4*)d_out, NTOT / 4);
}

// Round 2
// 1665.399 us; speedup vs baseline: 3.0451x; 3.0451x over previous
//
#include <hip/hip_runtime.h>
#include <math.h>

// InformationPlane: per 512-batch -> pdist2 GEMMs, sigma search, RBF Grams,
// 5x symmetric 512x512 eigvalsh (Jacobi w/ early exit), Renyi entropies, MI.
// d_out[0..NTOT) = x copy; d_out[NTOT]=Ixt_mean, d_out[NTOT+1]=Ity_mean.
// First 42MB of d_out double as matrix scratch before the final x copy.
//
// R2 change: Jacobi early-exit threshold 1e-11 -> 1e-8. Entropy error is
// 2nd-order in off-diag mass (~739*off2 ~= 7e-6 at threshold); worst-case
// 1st-order bound 7.56*sqrt(512*1e-8)=0.017 << 0.18 test threshold. R1 spent
// 3.5ms/dispatch spinning 30x511 rotation steps on Ay whose off2~1e-9.

#define NBATCH 8
#define MBS    512
#define DXX    8192
#define DII    3072
#define NSIG   50
#define NN     262144                 // 512*512
#define NTOT   ((size_t)33554432)     // 4096*8192

// scal (double) indices
#define I_SUMD  0    // 8
#define I_KYF   8    // 8
#define I_MEAND 16   // 8
#define I_SIGMA 24   // 8
#define I_ENT   32   // 40 (b*5+m)
#define I_NUM   96   // 8*50
#define I_DEN   512  // 8*50 -> ends 912

__device__ __forceinline__ size_t slotOf(int b, int m) {
  return ((size_t)(b * 5 + m)) * (size_t)NN;
}

// ---------------- copy x -> out ----------------
__global__ void k_copy(const float4* __restrict__ src, float4* __restrict__ dst, size_t n4) {
  size_t i = (size_t)blockIdx.x * blockDim.x + threadIdx.x;
  size_t stride = (size_t)gridDim.x * blockDim.x;
  for (; i < n4; i += stride) dst[i] = src[i];
}

// ---------------- row squared norms ----------------
__global__ void k_rownorm(const float* __restrict__ src, int D, float* __restrict__ out) {
  int row = blockIdx.x;
  const float* p = src + (size_t)row * D;
  double s = 0.0;
  for (int c = threadIdx.x; c < D; c += 256) { float v = p[c]; s += (double)v * v; }
  __shared__ double red[256];
  red[threadIdx.x] = s; __syncthreads();
  for (int o = 128; o > 0; o >>= 1) {
    if (threadIdx.x < o) red[threadIdx.x] += red[threadIdx.x + o];
    __syncthreads();
  }
  if (threadIdx.x == 0) out[row] = (float)red[0];
}

// ---------------- label kernel Ky (-> Ay slot), ||Ky||_F^2 ----------------
__global__ void k_ky(const float* __restrict__ lab, float* __restrict__ eig, double* __restrict__ scal) {
  int b = blockIdx.y;
  int e = blockIdx.x * 256 + threadIdx.x;   // 0..NN-1 (grid.x = 1024)
  int i = e >> 9, j = e & 511;
  const float* L = lab + (size_t)b * MBS * 10;
  float d2 = 0.0f;
#pragma unroll
  for (int d = 0; d < 10; d++) { float t = L[i * 10 + d] - L[j * 10 + d]; d2 += t * t; }
  float ky = __expf(-d2 * 100.0f);          // sigma = 0.1 -> /0.01
  eig[slotOf(b, 2) + e] = ky * (1.0f / 512.0f);   // Ay = Ky/n
  __shared__ double red[256];
  red[threadIdx.x] = (double)ky * ky; __syncthreads();
  for (int o = 128; o > 0; o >>= 1) {
    if (threadIdx.x < o) red[threadIdx.x] += red[threadIdx.x + o];
    __syncthreads();
  }
  if (threadIdx.x == 0) atomicAdd(&scal[I_KYF + b], red[0]);
}

// ---------------- pdist2 GEMM + epilogue ----------------
// MODE 0: x -> writes d2 into slot(b,1), fused sum(sqrt(d2)) & count(d2>0)
// MODE 1: input -> writes Ax = exp(-d2/64)/512 into slot(b,0)
template <int D, int MODE>
__global__ void k_gemm(const float* __restrict__ X, const float* __restrict__ nrm,
                       float* __restrict__ eig, double* __restrict__ scal,
                       unsigned long long* __restrict__ cnt) {
  int b = blockIdx.z;
  const float* Xb = X + (size_t)b * MBS * D;
  const float* nb = nrm + b * MBS;
  __shared__ float As[64][33];
  __shared__ float Bs[64][33];
  int tx = threadIdx.x, ty = threadIdx.y;
  int tid = ty * 16 + tx;
  int row0 = blockIdx.x * 64, col0 = blockIdx.y * 64;
  float acc[4][4] = {};
  for (int k0 = 0; k0 < D; k0 += 32) {
#pragma unroll
    for (int l = 0; l < 8; l++) {
      int idx = tid + l * 256; int r = idx >> 5, c = idx & 31;
      As[r][c] = Xb[(size_t)(row0 + r) * D + k0 + c];
      Bs[r][c] = Xb[(size_t)(col0 + r) * D + k0 + c];
    }
    __syncthreads();
#pragma unroll
    for (int kk = 0; kk < 32; kk++) {
      float a[4], bb[4];
#pragma unroll
      for (int i = 0; i < 4; i++) { a[i] = As[ty * 4 + i][kk]; bb[i] = Bs[tx * 4 + i][kk]; }
#pragma unroll
      for (int i = 0; i < 4; i++)
#pragma unroll
        for (int j = 0; j < 4; j++) acc[i][j] += a[i] * bb[j];
    }
    __syncthreads();
  }
  float* dst = eig + slotOf(b, (MODE == 0) ? 1 : 0);
  double lsum = 0.0; unsigned lcnt = 0;
#pragma unroll
  for (int i = 0; i < 4; i++) {
    int gi = row0 + ty * 4 + i;
#pragma unroll
    for (int j = 0; j < 4; j++) {
      int gj = col0 + tx * 4 + j;
      float d2 = nb[gi] + nb[gj] - 2.0f * acc[i][j];
      d2 = fmaxf(d2, 0.0f);
      if (gi == gj) d2 = 0.0f;     // force exact-zero diagonal
      if (MODE == 0) {
        dst[(size_t)gi * MBS + gj] = d2;
        if (d2 > 0.0f) { lsum += sqrt((double)d2); lcnt++; }
      } else {
        dst[(size_t)gi * MBS + gj] = __expf(-d2 * (1.0f / 64.0f)) * (1.0f / 512.0f);
      }
    }
  }
  if (MODE == 0) {
    __shared__ double redd[256];
    __shared__ unsigned redi[256];
    redd[tid] = lsum; redi[tid] = lcnt; __syncthreads();
    for (int o = 128; o > 0; o >>= 1) {
      if (tid < o) { redd[tid] += redd[tid + o]; redi[tid] += redi[tid + o]; }
      __syncthreads();
    }
    if (tid == 0) {
      atomicAdd(&scal[I_SUMD + b], redd[0]);
      atomicAdd(&cnt[b], (unsigned long long)redi[0]);
    }
  }
}

// ---------------- mean_d ----------------
__global__ void k_meand(double* __restrict__ scal, const unsigned long long* __restrict__ cnt) {
  int b = threadIdx.x;
  if (b < NBATCH) {
    double c = (double)cnt[b]; if (c < 1.0) c = 1.0;
    scal[I_MEAND + b] = scal[I_SUMD + b] / c;
  }
}

// ---------------- sigma-search sums ----------------
__global__ void k_loss(const float* __restrict__ eig, double* __restrict__ scal) {
  int b = blockIdx.z, s = blockIdx.y;
  float md = (float)scal[I_MEAND + b];
  float sg = md * (0.1f + 0.198f * (float)s);
  float inv = 1.0f / (sg * sg);
  const float* d2p = eig + slotOf(b, 1);
  const float* ayp = eig + slotOf(b, 2);
  size_t base = (size_t)blockIdx.x * 8192 + threadIdx.x;
  double ln = 0.0, ld = 0.0;
  for (int l = 0; l < 32; l++) {
    size_t e = base + (size_t)l * 256;
    float d2 = d2p[e];
    float ky = ayp[e] * 512.0f;
    float k = __expf(-d2 * inv);
    ln += (double)k * ky;
    ld += (double)k * k;
  }
  __shared__ double rn[256], rd[256];
  rn[threadIdx.x] = ln; rd[threadIdx.x] = ld; __syncthreads();
  for (int o = 128; o > 0; o >>= 1) {
    if (threadIdx.x < o) { rn[threadIdx.x] += rn[threadIdx.x + o]; rd[threadIdx.x] += rd[threadIdx.x + o]; }
    __syncthreads();
  }
  if (threadIdx.x == 0) {
    atomicAdd(&scal[I_NUM + b * NSIG + s], rn[0]);
    atomicAdd(&scal[I_DEN + b * NSIG + s], rd[0]);
  }
}

// ---------------- argmax + EMA sigma chain ----------------
__global__ void k_sigma(double* __restrict__ scal) {
  if (threadIdx.x == 0) {
    double sigma = 0.0;
    for (int b = 0; b < NBATCH; b++) {
      double kyf = sqrt(scal[I_KYF + b]);
      double best = -1.0; int bi = 0;
      for (int s = 0; s < NSIG; s++) {
        double num = scal[I_NUM + b * NSIG + s];
        double den = sqrt(scal[I_DEN + b * NSIG + s]) * kyf;
        double loss = num / den;
        if (loss > best) { best = loss; bi = s; }
      }
      double md = scal[I_MEAND + b];
      double st = md * (0.1 + 0.198 * (double)bi);
      sigma = (b == 0) ? st : 0.5 * sigma + 0.5 * st;
      scal[I_SIGMA + b] = sigma;
    }
  }
}

// ---------------- A = exp(-d2/sigma^2)/n, in place over slot(b,1) ----------------
__global__ void k_abuild(float* __restrict__ eig, const double* __restrict__ scal) {
  int b = blockIdx.y;
  float sg = (float)scal[I_SIGMA + b];
  float inv = 1.0f / (sg * sg);
  size_t e = (size_t)blockIdx.x * 256 + threadIdx.x;
  float* A = eig + slotOf(b, 1);
  A[e] = __expf(-A[e] * inv) * (1.0f / 512.0f);
}

// ---------------- Schur products ----------------
__global__ void k_joints(float* __restrict__ eig) {
  int b = blockIdx.y;
  size_t e = (size_t)blockIdx.x * 256 + threadIdx.x;
  float ax = eig[slotOf(b, 0) + e];
  float a  = eig[slotOf(b, 1) + e];
  float ay = eig[slotOf(b, 2) + e];
  eig[slotOf(b, 3) + e] = ax * a;
  eig[slotOf(b, 4) + e] = a * ay;
}

// ---------------- symmetric eigenvalues (threshold Jacobi) + entropy ----------------
__global__ __launch_bounds__(512) void k_eigen(float* __restrict__ eig, double* __restrict__ scal) {
  int blk = blockIdx.x; int b = blk / 5, m = blk % 5;
  float* M = eig + slotOf(b, m);
  int t = threadIdx.x;
  __shared__ double red[512];
  __shared__ float csA[256], csB[256];
  __shared__ int anyrot;
  __shared__ double sh_scale, sh_off2;

  // trace (of raw matrix; Jacobi preserves it)
  red[t] = (double)M[(size_t)t * 513]; __syncthreads();
  for (int o = 256; o > 0; o >>= 1) { if (t < o) red[t] += red[t + o]; __syncthreads(); }
  if (t == 0) { double trace = red[0]; sh_scale = (m >= 3) ? 1.0 / trace : 1.0; }
  __syncthreads();
  double scale = sh_scale;

  for (int sweep = 0; sweep < 30; sweep++) {
    // off-diagonal Frobenius^2 (column-wise, coalesced)
    double s2 = 0.0;
    for (int i = 0; i < 512; i++) {
      if (i != t) { float v = M[(size_t)i * 512 + t]; s2 += (double)v * v; }
    }
    red[t] = s2; __syncthreads();
    for (int o = 256; o > 0; o >>= 1) { if (t < o) red[t] += red[t + o]; __syncthreads(); }
    if (t == 0) sh_off2 = red[0];
    __syncthreads();
    // entropy error is 2nd-order: ~739*off2 ~ 7e-6 at this threshold
    if (sh_off2 * scale * scale <= 1e-8) break;

    for (int r = 0; r < 511; r++) {
      if (t == 0) anyrot = 0;
      __syncthreads();
      if (t < 256) {
        int p, q;
        if (t == 0) { p = 511; q = r; }
        else { p = (r + t) % 511; q = (r + 511 - t) % 511; }
        float app = M[(size_t)p * 512 + p];
        float aqq = M[(size_t)q * 512 + q];
        float apq = M[(size_t)p * 512 + q];
        float c = 1.0f, sr = 0.0f;
        if (fabsf(apq) > 1e-12f) {
          float th = (aqq - app) / (2.0f * apq);
          float tt = ((th >= 0.0f) ? 1.0f : -1.0f) / (fabsf(th) + sqrtf(1.0f + th * th));
          c = 1.0f / sqrtf(1.0f + tt * tt);
          sr = tt * c;
          anyrot = 1;
        }
        csA[t] = c; csB[t] = sr;
      }
      __syncthreads();
      if (anyrot) {
        int pair = t >> 1, half = t & 1;
        float c = csA[pair], sr = csB[pair];
        int p, q;
        if (pair == 0) { p = 511; q = r; }
        else { p = (r + pair) % 511; q = (r + 511 - pair) % 511; }
        if (sr != 0.0f) {   // rows: J^T A
          size_t rp = (size_t)p * 512, rq = (size_t)q * 512;
          int j0 = half * 256;
          for (int j = j0; j < j0 + 256; j++) {
            float xx = M[rp + j], yy = M[rq + j];
            M[rp + j] = c * xx - sr * yy;
            M[rq + j] = sr * xx + c * yy;
          }
        }
        __syncthreads();
        if (sr != 0.0f) {   // cols: (J^T A) J
          int j0 = half * 256;
          for (int j = j0; j < j0 + 256; j++) {
            float xx = M[(size_t)j * 512 + p], yy = M[(size_t)j * 512 + q];
            M[(size_t)j * 512 + p] = c * xx - sr * yy;
            M[(size_t)j * 512 + q] = sr * xx + c * yy;
          }
        }
      }
      __syncthreads();
    }
  }

  // entropy from (near-)diagonal
  double w = (double)M[(size_t)t * 513] * scale + 1e-6;
  red[t] = -w * log2(w); __syncthreads();
  for (int o = 256; o > 0; o >>= 1) { if (t < o) red[t] += red[t + o]; __syncthreads(); }
  if (t == 0) scal[I_ENT + b * 5 + m] = red[0];
}

// ---------------- finalize MI means ----------------
__global__ void k_final(const double* __restrict__ scal, float* __restrict__ out) {
  if (threadIdx.x == 0) {
    double ixt = 0.0, ity = 0.0;
    for (int b = 0; b < NBATCH; b++) {
      const double* E = &scal[I_ENT + b * 5];
      ixt += E[0] + E[1] - E[3];
      ity += E[1] + E[2] - E[4];
    }
    out[NTOT]     = (float)(ixt / 8.0);
    out[NTOT + 1] = (float)(ity / 8.0);
  }
}

extern "C" void kernel_launch(void* const* d_in, const int* in_sizes, int n_in,
                              void* d_out, int out_size, void* d_ws, size_t ws_size,
                              hipStream_t stream) {
  const float* x   = (const float*)d_in[0];
  const float* inp = (const float*)d_in[1];
  const float* lab = (const float*)d_in[2];
  float* out = (float*)d_out;

  // Matrix scratch lives in d_out (first 42MB of the 134MB x-region);
  // the x copy happens last. d_ws only holds small scalars/norms.
  float* eig = (float*)d_out;
  char* ws = (char*)d_ws;
  double* scal = (double*)ws;                                  // 8 KB
  unsigned long long* cnt = (unsigned long long*)(ws + 8192);  // 64 B
  float* nrmx = (float*)(ws + 8192 + 256);                     // 16 KB
  float* nrmi = nrmx + 4096;                                   // 12 KB used of 16

  hipMemsetAsync(ws, 0, 8192 + 256, stream);

  k_rownorm<<<4096, 256, 0, stream>>>(x,   DXX, nrmx);
  k_rownorm<<<4096, 256, 0, stream>>>(inp, DII, nrmi);
  k_ky<<<dim3(1024, NBATCH), 256, 0, stream>>>(lab, eig, scal);
  k_gemm<DXX, 0><<<dim3(8, 8, NBATCH), dim3(16, 16), 0, stream>>>(x,   nrmx, eig, scal, cnt);
  k_gemm<DII, 1><<<dim3(8, 8, NBATCH), dim3(16, 16), 0, stream>>>(inp, nrmi, eig, scal, cnt);
  k_meand<<<1, 64, 0, stream>>>(scal, cnt);
  k_loss<<<dim3(32, NSIG, NBATCH), 256, 0, stream>>>(eig, scal);
  k_sigma<<<1, 64, 0, stream>>>(scal);
  k_abuild<<<dim3(1024, NBATCH), 256, 0, stream>>>(eig, scal);
  k_joints<<<dim3(1024, NBATCH), 256, 0, stream>>>(eig);
  k_eigen<<<40, 512, 0, stream>>>(eig, scal);
  k_final<<<1, 64, 0, stream>>>(scal, out);
  // x copy LAST (overwrites the matrix scratch region)
  k_copy<<<2048, 256, 0, stream>>>((const float4*)x, (float4*)d_out, NTOT / 4);
}

// Round 3
// 682.744 us; speedup vs baseline: 7.4279x; 2.4393x over previous
//
#include <hip/hip_runtime.h>
#include <hip/hip_bf16.h>
#include <math.h>

// InformationPlane: per 512-batch -> pdist2 GEMMs (bf16 MFMA), sigma search,
// RBF Grams, 5x symmetric 512x512 eigvalsh (Jacobi w/ early exit), Renyi
// entropies, MI. d_out[0..NTOT) = x copy; d_out[NTOT]=Ixt, d_out[NTOT+1]=Ity.
// First 42MB of d_out double as matrix scratch before the final x copy.
//
// R3: both pdist2 GEMMs -> one fused bf16-MFMA kernel (16x16x32, 128^2 tile,
// BK=64, reg-staged fp32->bf16 into LDS stride-72 (144B rows: 16B-aligned,
// bank-balanced)). bf16 d2 error ~0.3 / 16384 -> negligible vs 0.18 thresh.

#define NBATCH 8
#define MBS    512
#define DXX    8192
#define DII    3072
#define NSIG   50
#define NN     262144                 // 512*512
#define NTOT   ((size_t)33554432)     // 4096*8192

// scal (double) indices
#define I_SUMD  0    // 8
#define I_KYF   8    // 8
#define I_MEAND 16   // 8
#define I_SIGMA 24   // 8
#define I_ENT   32   // 40 (b*5+m)
#define I_NUM   96   // 8*50
#define I_DEN   512  // 8*50 -> ends 912

typedef __attribute__((ext_vector_type(8))) short bf16x8;
typedef __attribute__((ext_vector_type(4))) float f32x4;

__device__ __forceinline__ size_t slotOf(int b, int m) {
  return ((size_t)(b * 5 + m)) * (size_t)NN;
}

__device__ __forceinline__ short f2b(float f) {
  __hip_bfloat16 h = __float2bfloat16(f);   // compiler fuses pairs to v_cvt_pk_bf16_f32
  return *(short*)&h;
}

// ---------------- copy x -> out ----------------
__global__ void k_copy(const float4* __restrict__ src, float4* __restrict__ dst, size_t n4) {
  size_t i = (size_t)blockIdx.x * blockDim.x + threadIdx.x;
  size_t stride = (size_t)gridDim.x * blockDim.x;
  for (; i < n4; i += stride) dst[i] = src[i];
}

// ---------------- row squared norms ----------------
__global__ void k_rownorm(const float* __restrict__ src, int D, float* __restrict__ out) {
  int row = blockIdx.x;
  const float* p = src + (size_t)row * D;
  double s = 0.0;
  for (int c = threadIdx.x; c < D; c += 256) { float v = p[c]; s += (double)v * v; }
  __shared__ double red[256];
  red[threadIdx.x] = s; __syncthreads();
  for (int o = 128; o > 0; o >>= 1) {
    if (threadIdx.x < o) red[threadIdx.x] += red[threadIdx.x + o];
    __syncthreads();
  }
  if (threadIdx.x == 0) out[row] = (float)red[0];
}

// ---------------- label kernel Ky (-> Ay slot), ||Ky||_F^2 ----------------
__global__ void k_ky(const float* __restrict__ lab, float* __restrict__ eig, double* __restrict__ scal) {
  int b = blockIdx.y;
  int e = blockIdx.x * 256 + threadIdx.x;   // 0..NN-1 (grid.x = 1024)
  int i = e >> 9, j = e & 511;
  const float* L = lab + (size_t)b * MBS * 10;
  float d2 = 0.0f;
#pragma unroll
  for (int d = 0; d < 10; d++) { float t = L[i * 10 + d] - L[j * 10 + d]; d2 += t * t; }
  float ky = __expf(-d2 * 100.0f);          // sigma = 0.1 -> /0.01
  eig[slotOf(b, 2) + e] = ky * (1.0f / 512.0f);   // Ay = Ky/n
  __shared__ double red[256];
  red[threadIdx.x] = (double)ky * ky; __syncthreads();
  for (int o = 128; o > 0; o >>= 1) {
    if (threadIdx.x < o) red[threadIdx.x] += red[threadIdx.x + o];
    __syncthreads();
  }
  if (threadIdx.x == 0) atomicAdd(&scal[I_KYF + b], red[0]);
}

// ---------------- fused bf16-MFMA pdist2 GEMM ----------------
// z = blockIdx.z: z<8 -> batch z of x (D=8192): write d2 to slot(b,1) + fused
// sum(sqrt(d2)),count(d2>0). z>=8 -> batch z-8 of input (D=3072): write
// Ax = exp(-d2/64)/512 to slot(b,0).
// 128x128 tile, BK=64, 256 thr (4 waves, 2x2), wave = 64x64 = 4x4 frags.
#define LSTR 72   // ushorts per LDS row: 144B = 16B-aligned, bank-balanced
__global__ __launch_bounds__(256) void k_gemm2(
    const float* __restrict__ X, const float* __restrict__ Inp,
    const float* __restrict__ nrmx, const float* __restrict__ nrmi,
    float* __restrict__ eig, double* __restrict__ scal,
    unsigned long long* __restrict__ cnt)
{
  int z = blockIdx.z; int b = z & 7; int mode = z >> 3;
  int D = mode ? DII : DXX;
  const float* src = (mode ? Inp : X) + (size_t)b * MBS * D;
  const float* nb  = (mode ? nrmi : nrmx) + b * MBS;
  int row0 = blockIdx.x * 128, col0 = blockIdx.y * 128;

  __shared__ ushort As[128 * LSTR];
  __shared__ ushort Bs[128 * LSTR];
  __shared__ double redd[256];
  __shared__ unsigned redi[256];

  int tid = threadIdx.x;
  int lane = tid & 63, w = tid >> 6;
  int wr = (w >> 1) * 64, wc = (w & 1) * 64;
  int l15 = lane & 15, l4 = lane >> 4;

  f32x4 acc[4][4];
  const f32x4 zero = {0.f, 0.f, 0.f, 0.f};
#pragma unroll
  for (int m = 0; m < 4; m++)
#pragma unroll
    for (int n = 0; n < 4; n++) acc[m][n] = zero;

  int rr = tid >> 3;            // 0..31
  int cc = (tid & 7) * 8;       // element col 0..56

  for (int k0 = 0; k0 < D; k0 += 64) {
    __syncthreads();
#pragma unroll
    for (int c = 0; c < 4; c++) {
      int r = c * 32 + rr;
      const float4* pa = (const float4*)(src + (size_t)(row0 + r) * D + k0 + cc);
      const float4* pb = (const float4*)(src + (size_t)(col0 + r) * D + k0 + cc);
      float4 a0 = pa[0], a1 = pa[1];
      float4 b0 = pb[0], b1 = pb[1];
      bf16x8 va, vb;
      va[0] = f2b(a0.x); va[1] = f2b(a0.y); va[2] = f2b(a0.z); va[3] = f2b(a0.w);
      va[4] = f2b(a1.x); va[5] = f2b(a1.y); va[6] = f2b(a1.z); va[7] = f2b(a1.w);
      vb[0] = f2b(b0.x); vb[1] = f2b(b0.y); vb[2] = f2b(b0.z); vb[3] = f2b(b0.w);
      vb[4] = f2b(b1.x); vb[5] = f2b(b1.y); vb[6] = f2b(b1.z); vb[7] = f2b(b1.w);
      *(bf16x8*)&As[r * LSTR + cc] = va;
      *(bf16x8*)&Bs[r * LSTR + cc] = vb;
    }
    __syncthreads();
#pragma unroll
    for (int ks = 0; ks < 2; ks++) {
      bf16x8 af[4], bf[4];
#pragma unroll
      for (int m = 0; m < 4; m++)
        af[m] = *(const bf16x8*)&As[(wr + m * 16 + l15) * LSTR + ks * 32 + l4 * 8];
#pragma unroll
      for (int n = 0; n < 4; n++)
        bf[n] = *(const bf16x8*)&Bs[(wc + n * 16 + l15) * LSTR + ks * 32 + l4 * 8];
#pragma unroll
      for (int m = 0; m < 4; m++)
#pragma unroll
        for (int n = 0; n < 4; n++)
          acc[m][n] = __builtin_amdgcn_mfma_f32_16x16x32_bf16(af[m], bf[n], acc[m][n], 0, 0, 0);
    }
  }

  // epilogue: d2 = |xi|^2 + |xj|^2 - 2 xi.xj  (C/D layout: col=lane&15, row=(lane>>4)*4+v)
  float* dst = eig + slotOf(b, mode ? 0 : 1);
  double lsum = 0.0; unsigned lcnt = 0;
#pragma unroll
  for (int m = 0; m < 4; m++) {
    int gr = row0 + wr + m * 16 + l4 * 4;
#pragma unroll
    for (int n = 0; n < 4; n++) {
      int gc = col0 + wc + n * 16 + l15;
      float nj = nb[gc];
#pragma unroll
      for (int v = 0; v < 4; v++) {
        int gi = gr + v;
        float d2 = nb[gi] + nj - 2.0f * acc[m][n][v];
        d2 = fmaxf(d2, 0.0f);
        if (gi == gc) d2 = 0.0f;
        if (mode == 0) {
          dst[(size_t)gi * MBS + gc] = d2;
          if (d2 > 0.0f) { lsum += (double)sqrtf(d2); lcnt++; }
        } else {
          dst[(size_t)gi * MBS + gc] = __expf(-d2 * (1.0f / 64.0f)) * (1.0f / 512.0f);
        }
      }
    }
  }
  if (mode == 0) {
    redd[tid] = lsum; redi[tid] = lcnt; __syncthreads();
    for (int o = 128; o > 0; o >>= 1) {
      if (tid < o) { redd[tid] += redd[tid + o]; redi[tid] += redi[tid + o]; }
      __syncthreads();
    }
    if (tid == 0) {
      atomicAdd(&scal[I_SUMD + b], redd[0]);
      atomicAdd(&cnt[b], (unsigned long long)redi[0]);
    }
  }
}

// ---------------- mean_d ----------------
__global__ void k_meand(double* __restrict__ scal, const unsigned long long* __restrict__ cnt) {
  int b = threadIdx.x;
  if (b < NBATCH) {
    double c = (double)cnt[b]; if (c < 1.0) c = 1.0;
    scal[I_MEAND + b] = scal[I_SUMD + b] / c;
  }
}

// ---------------- sigma-search sums ----------------
__global__ void k_loss(const float* __restrict__ eig, double* __restrict__ scal) {
  int b = blockIdx.z, s = blockIdx.y;
  float md = (float)scal[I_MEAND + b];
  float sg = md * (0.1f + 0.198f * (float)s);
  float inv = 1.0f / (sg * sg);
  const float* d2p = eig + slotOf(b, 1);
  const float* ayp = eig + slotOf(b, 2);
  size_t base = (size_t)blockIdx.x * 8192 + threadIdx.x;
  double ln = 0.0, ld = 0.0;
  for (int l = 0; l < 32; l++) {
    size_t e = base + (size_t)l * 256;
    float d2 = d2p[e];
    float ky = ayp[e] * 512.0f;
    float k = __expf(-d2 * inv);
    ln += (double)k * ky;
    ld += (double)k * k;
  }
  __shared__ double rn[256], rd[256];
  rn[threadIdx.x] = ln; rd[threadIdx.x] = ld; __syncthreads();
  for (int o = 128; o > 0; o >>= 1) {
    if (threadIdx.x < o) { rn[threadIdx.x] += rn[threadIdx.x + o]; rd[threadIdx.x] += rd[threadIdx.x + o]; }
    __syncthreads();
  }
  if (threadIdx.x == 0) {
    atomicAdd(&scal[I_NUM + b * NSIG + s], rn[0]);
    atomicAdd(&scal[I_DEN + b * NSIG + s], rd[0]);
  }
}

// ---------------- argmax + EMA sigma chain ----------------
__global__ void k_sigma(double* __restrict__ scal) {
  if (threadIdx.x == 0) {
    double sigma = 0.0;
    for (int b = 0; b < NBATCH; b++) {
      double kyf = sqrt(scal[I_KYF + b]);
      double best = -1.0; int bi = 0;
      for (int s = 0; s < NSIG; s++) {
        double num = scal[I_NUM + b * NSIG + s];
        double den = sqrt(scal[I_DEN + b * NSIG + s]) * kyf;
        double loss = num / den;
        if (loss > best) { best = loss; bi = s; }
      }
      double md = scal[I_MEAND + b];
      double st = md * (0.1 + 0.198 * (double)bi);
      sigma = (b == 0) ? st : 0.5 * sigma + 0.5 * st;
      scal[I_SIGMA + b] = sigma;
    }
  }
}

// ---------------- A = exp(-d2/sigma^2)/n, in place over slot(b,1) ----------------
__global__ void k_abuild(float* __restrict__ eig, const double* __restrict__ scal) {
  int b = blockIdx.y;
  float sg = (float)scal[I_SIGMA + b];
  float inv = 1.0f / (sg * sg);
  size_t e = (size_t)blockIdx.x * 256 + threadIdx.x;
  float* A = eig + slotOf(b, 1);
  A[e] = __expf(-A[e] * inv) * (1.0f / 512.0f);
}

// ---------------- Schur products ----------------
__global__ void k_joints(float* __restrict__ eig) {
  int b = blockIdx.y;
  size_t e = (size_t)blockIdx.x * 256 + threadIdx.x;
  float ax = eig[slotOf(b, 0) + e];
  float a  = eig[slotOf(b, 1) + e];
  float ay = eig[slotOf(b, 2) + e];
  eig[slotOf(b, 3) + e] = ax * a;
  eig[slotOf(b, 4) + e] = a * ay;
}

// ---------------- symmetric eigenvalues (threshold Jacobi) + entropy ----------------
__global__ __launch_bounds__(512) void k_eigen(float* __restrict__ eig, double* __restrict__ scal) {
  int blk = blockIdx.x; int b = blk / 5, m = blk % 5;
  float* M = eig + slotOf(b, m);
  int t = threadIdx.x;
  __shared__ double red[512];
  __shared__ float csA[256], csB[256];
  __shared__ int anyrot;
  __shared__ double sh_scale, sh_off2;

  // trace (of raw matrix; Jacobi preserves it)
  red[t] = (double)M[(size_t)t * 513]; __syncthreads();
  for (int o = 256; o > 0; o >>= 1) { if (t < o) red[t] += red[t + o]; __syncthreads(); }
  if (t == 0) { double trace = red[0]; sh_scale = (m >= 3) ? 1.0 / trace : 1.0; }
  __syncthreads();
  double scale = sh_scale;

  for (int sweep = 0; sweep < 30; sweep++) {
    // off-diagonal Frobenius^2 (column-wise, coalesced)
    double s2 = 0.0;
    for (int i = 0; i < 512; i++) {
      if (i != t) { float v = M[(size_t)i * 512 + t]; s2 += (double)v * v; }
    }
    red[t] = s2; __syncthreads();
    for (int o = 256; o > 0; o >>= 1) { if (t < o) red[t] += red[t + o]; __syncthreads(); }
    if (t == 0) sh_off2 = red[0];
    __syncthreads();
    // entropy error is 2nd-order: ~739*off2 ~ 7e-6 at this threshold
    if (sh_off2 * scale * scale <= 1e-8) break;

    for (int r = 0; r < 511; r++) {
      if (t == 0) anyrot = 0;
      __syncthreads();
      if (t < 256) {
        int p, q;
        if (t == 0) { p = 511; q = r; }
        else { p = (r + t) % 511; q = (r + 511 - t) % 511; }
        float app = M[(size_t)p * 512 + p];
        float aqq = M[(size_t)q * 512 + q];
        float apq = M[(size_t)p * 512 + q];
        float c = 1.0f, sr = 0.0f;
        if (fabsf(apq) > 1e-12f) {
          float th = (aqq - app) / (2.0f * apq);
          float tt = ((th >= 0.0f) ? 1.0f : -1.0f) / (fabsf(th) + sqrtf(1.0f + th * th));
          c = 1.0f / sqrtf(1.0f + tt * tt);
          sr = tt * c;
          anyrot = 1;
        }
        csA[t] = c; csB[t] = sr;
      }
      __syncthreads();
      if (anyrot) {
        int pair = t >> 1, half = t & 1;
        float c = csA[pair], sr = csB[pair];
        int p, q;
        if (pair == 0) { p = 511; q = r; }
        else { p = (r + pair) % 511; q = (r + 511 - pair) % 511; }
        if (sr != 0.0f) {   // rows: J^T A
          size_t rp = (size_t)p * 512, rq = (size_t)q * 512;
          int j0 = half * 256;
          for (int j = j0; j < j0 + 256; j++) {
            float xx = M[rp + j], yy = M[rq + j];
            M[rp + j] = c * xx - sr * yy;
            M[rq + j] = sr * xx + c * yy;
          }
        }
        __syncthreads();
        if (sr != 0.0f) {   // cols: (J^T A) J
          int j0 = half * 256;
          for (int j = j0; j < j0 + 256; j++) {
            float xx = M[(size_t)j * 512 + p], yy = M[(size_t)j * 512 + q];
            M[(size_t)j * 512 + p] = c * xx - sr * yy;
            M[(size_t)j * 512 + q] = sr * xx + c * yy;
          }
        }
      }
      __syncthreads();
    }
  }

  // entropy from (near-)diagonal
  double w = (double)M[(size_t)t * 513] * scale + 1e-6;
  red[t] = -w * log2(w); __syncthreads();
  for (int o = 256; o > 0; o >>= 1) { if (t < o) red[t] += red[t + o]; __syncthreads(); }
  if (t == 0) scal[I_ENT + b * 5 + m] = red[0];
}

// ---------------- finalize MI means ----------------
__global__ void k_final(const double* __restrict__ scal, float* __restrict__ out) {
  if (threadIdx.x == 0) {
    double ixt = 0.0, ity = 0.0;
    for (int b = 0; b < NBATCH; b++) {
      const double* E = &scal[I_ENT + b * 5];
      ixt += E[0] + E[1] - E[3];
      ity += E[1] + E[2] - E[4];
    }
    out[NTOT]     = (float)(ixt / 8.0);
    out[NTOT + 1] = (float)(ity / 8.0);
  }
}

extern "C" void kernel_launch(void* const* d_in, const int* in_sizes, int n_in,
                              void* d_out, int out_size, void* d_ws, size_t ws_size,
                              hipStream_t stream) {
  const float* x   = (const float*)d_in[0];
  const float* inp = (const float*)d_in[1];
  const float* lab = (const float*)d_in[2];
  float* out = (float*)d_out;

  // Matrix scratch lives in d_out (first 42MB of the 134MB x-region);
  // the x copy happens last. d_ws only holds small scalars/norms.
  float* eig = (float*)d_out;
  char* ws = (char*)d_ws;
  double* scal = (double*)ws;                                  // 8 KB
  unsigned long long* cnt = (unsigned long long*)(ws + 8192);  // 64 B
  float* nrmx = (float*)(ws + 8192 + 256);                     // 16 KB
  float* nrmi = nrmx + 4096;                                   // 12 KB used of 16

  hipMemsetAsync(ws, 0, 8192 + 256, stream);

  k_rownorm<<<4096, 256, 0, stream>>>(x,   DXX, nrmx);
  k_rownorm<<<4096, 256, 0, stream>>>(inp, DII, nrmi);
  k_ky<<<dim3(1024, NBATCH), 256, 0, stream>>>(lab, eig, scal);
  k_gemm2<<<dim3(4, 4, 16), 256, 0, stream>>>(x, inp, nrmx, nrmi, eig, scal, cnt);
  k_meand<<<1, 64, 0, stream>>>(scal, cnt);
  k_loss<<<dim3(32, NSIG, NBATCH), 256, 0, stream>>>(eig, scal);
  k_sigma<<<1, 64, 0, stream>>>(scal);
  k_abuild<<<dim3(1024, NBATCH), 256, 0, stream>>>(eig, scal);
  k_joints<<<dim3(1024, NBATCH), 256, 0, stream>>>(eig);
  k_eigen<<<40, 512, 0, stream>>>(eig, scal);
  k_final<<<1, 64, 0, stream>>>(scal, out);
  // x copy LAST (overwrites the matrix scratch region)
  k_copy<<<2048, 256, 0, stream>>>((const float4*)x, (float4*)d_out, NTOT / 4);
}

// Round 4
// 633.856 us; speedup vs baseline: 8.0008x; 1.0771x over previous
//
#include <hip/hip_runtime.h>
#include <hip/hip_bf16.h>
#include <math.h>

// InformationPlane: per 512-batch -> pdist2 GEMMs (bf16 MFMA), sigma search,
// RBF Grams, 5x symmetric 512x512 eigvalsh (Jacobi w/ early exit), Renyi
// entropies, MI. d_out[0..NTOT) = x copy; d_out[NTOT]=Ixt, d_out[NTOT+1]=Ity.
//
// R4: gemm2 pipelined (512 thr, dbuf LDS, reg prefetch, 1 barrier/K-step);
// k_loss 10-sigmas/block; abuild+joints fused; x-copy fused into rownorm when
// ws_size fits the 40MB matrix scratch (fallback: scratch in d_out, copy last).

#define NBATCH 8
#define MBS    512
#define DXX    8192
#define DII    3072
#define NSIG   50
#define NN     262144                 // 512*512
#define NTOT   ((size_t)33554432)     // 4096*8192

// scal (double) indices
#define I_SUMD  0    // 8
#define I_KYF   8    // 8
#define I_SIGMA 24   // 8
#define I_ENT   32   // 40 (b*5+m)
#define I_NUM   96   // 8*50
#define I_DEN   512  // 8*50 -> ends 912

typedef __attribute__((ext_vector_type(8))) short bf16x8;
typedef __attribute__((ext_vector_type(4))) float f32x4;

__device__ __forceinline__ size_t slotOf(int b, int m) {
  return ((size_t)(b * 5 + m)) * (size_t)NN;
}

__device__ __forceinline__ short f2b(float f) {
  __hip_bfloat16 h = __float2bfloat16(f);   // pairs fuse to v_cvt_pk_bf16_f32
  return *(short*)&h;
}

// ---------------- copy x -> out (fallback path only) ----------------
__global__ void k_copy(const float4* __restrict__ src, float4* __restrict__ dst, size_t n4) {
  size_t i = (size_t)blockIdx.x * blockDim.x + threadIdx.x;
  size_t stride = (size_t)gridDim.x * blockDim.x;
  for (; i < n4; i += stride) dst[i] = src[i];
}

// ---------------- row squared norms ----------------
__global__ void k_rownorm(const float* __restrict__ src, int D, float* __restrict__ out) {
  int row = blockIdx.x;
  const float* p = src + (size_t)row * D;
  double s = 0.0;
  for (int c = threadIdx.x; c < D; c += 256) { float v = p[c]; s += (double)v * v; }
  __shared__ double red[256];
  red[threadIdx.x] = s; __syncthreads();
  for (int o = 128; o > 0; o >>= 1) {
    if (threadIdx.x < o) red[threadIdx.x] += red[threadIdx.x + o];
    __syncthreads();
  }
  if (threadIdx.x == 0) out[row] = (float)red[0];
}

// ---------------- row norms fused with x->out copy (D=8192) ----------------
__global__ void k_rownorm_copy(const float4* __restrict__ src, float4* __restrict__ dst,
                               float* __restrict__ out) {
  int row = blockIdx.x;
  const float4* p = src + (size_t)row * 2048;
  float4* q = dst + (size_t)row * 2048;
  double s = 0.0;
#pragma unroll
  for (int l = 0; l < 8; l++) {
    int c = threadIdx.x + l * 256;
    float4 v = p[c];
    q[c] = v;
    s += (double)v.x * v.x + (double)v.y * v.y + (double)v.z * v.z + (double)v.w * v.w;
  }
  __shared__ double red[256];
  red[threadIdx.x] = s; __syncthreads();
  for (int o = 128; o > 0; o >>= 1) {
    if (threadIdx.x < o) red[threadIdx.x] += red[threadIdx.x + o];
    __syncthreads();
  }
  if (threadIdx.x == 0) out[row] = (float)red[0];
}

// ---------------- label kernel Ky (-> Ay slot), ||Ky||_F^2 ----------------
__global__ void k_ky(const float* __restrict__ lab, float* __restrict__ eig, double* __restrict__ scal) {
  int b = blockIdx.y;
  int e = blockIdx.x * 256 + threadIdx.x;   // grid.x = 1024
  int i = e >> 9, j = e & 511;
  const float* L = lab + (size_t)b * MBS * 10;
  float d2 = 0.0f;
#pragma unroll
  for (int d = 0; d < 10; d++) { float t = L[i * 10 + d] - L[j * 10 + d]; d2 += t * t; }
  float ky = __expf(-d2 * 100.0f);          // sigma = 0.1 -> /0.01
  eig[slotOf(b, 2) + e] = ky * (1.0f / 512.0f);   // Ay = Ky/n
  __shared__ double red[256];
  red[threadIdx.x] = (double)ky * ky; __syncthreads();
  for (int o = 128; o > 0; o >>= 1) {
    if (threadIdx.x < o) red[threadIdx.x] += red[threadIdx.x + o];
    __syncthreads();
  }
  if (threadIdx.x == 0) atomicAdd(&scal[I_KYF + b], red[0]);
}

// ---------------- fused bf16-MFMA pdist2 GEMM, pipelined ----------------
// z<8: batch z of x (D=8192) -> d2 to slot(b,1) + fused sum(sqrt),count.
// z>=8: batch z-8 of input (D=3072) -> Ax = exp(-d2/64)/512 to slot(b,0).
// 128x128 tile, BK=64, 512 thr (8 waves 2x4, wave tile 64x32 = 4x2 frags).
// Double-buffered LDS + register prefetch of next K-step; 1 barrier/K-step.
#define LSTR 72   // ushorts per LDS row: 144B = 16B-aligned, bank-quad-balanced
__global__ __launch_bounds__(512) void k_gemm2(
    const float* __restrict__ X, const float* __restrict__ Inp,
    const float* __restrict__ nrmx, const float* __restrict__ nrmi,
    float* __restrict__ eig, double* __restrict__ scal,
    unsigned long long* __restrict__ cnt)
{
  int z = blockIdx.z; int b = z & 7; int mode = z >> 3;
  int D = mode ? DII : DXX;
  const float* src = (mode ? Inp : X) + (size_t)b * MBS * D;
  const float* nb  = (mode ? nrmi : nrmx) + b * MBS;
  int row0 = blockIdx.x * 128, col0 = blockIdx.y * 128;

  __shared__ ushort As[2][128 * LSTR];
  __shared__ ushort Bs[2][128 * LSTR];
  __shared__ double redd[512];
  __shared__ unsigned redi[512];

  int tid = threadIdx.x;
  int lane = tid & 63, w = tid >> 6;
  int wr = (w >> 2) * 64, wc = (w & 3) * 32;
  int l15 = lane & 15, l4 = lane >> 4;

  f32x4 acc[4][2];
#pragma unroll
  for (int m = 0; m < 4; m++)
#pragma unroll
    for (int n = 0; n < 2; n++) {
      acc[m][n][0] = 0.f; acc[m][n][1] = 0.f; acc[m][n][2] = 0.f; acc[m][n][3] = 0.f;
    }

  int rr = tid >> 3;            // 0..63
  int cc = (tid & 7) * 8;       // 0..56

  float4 ra[2][2], rb[2][2];
  auto loadk = [&](int k0) {
#pragma unroll
    for (int c = 0; c < 2; c++) {
      int r = c * 64 + rr;
      const float4* pa = (const float4*)(src + (size_t)(row0 + r) * D + k0 + cc);
      const float4* pb = (const float4*)(src + (size_t)(col0 + r) * D + k0 + cc);
      ra[c][0] = pa[0]; ra[c][1] = pa[1];
      rb[c][0] = pb[0]; rb[c][1] = pb[1];
    }
  };

  loadk(0);
  int nk = D >> 6;
  for (int k = 0; k < nk; k++) {
    int buf = k & 1;
#pragma unroll
    for (int c = 0; c < 2; c++) {
      int r = c * 64 + rr;
      bf16x8 va, vb;
      va[0] = f2b(ra[c][0].x); va[1] = f2b(ra[c][0].y); va[2] = f2b(ra[c][0].z); va[3] = f2b(ra[c][0].w);
      va[4] = f2b(ra[c][1].x); va[5] = f2b(ra[c][1].y); va[6] = f2b(ra[c][1].z); va[7] = f2b(ra[c][1].w);
      vb[0] = f2b(rb[c][0].x); vb[1] = f2b(rb[c][0].y); vb[2] = f2b(rb[c][0].z); vb[3] = f2b(rb[c][0].w);
      vb[4] = f2b(rb[c][1].x); vb[5] = f2b(rb[c][1].y); vb[6] = f2b(rb[c][1].z); vb[7] = f2b(rb[c][1].w);
      *(bf16x8*)&As[buf][r * LSTR + cc] = va;
      *(bf16x8*)&Bs[buf][r * LSTR + cc] = vb;
    }
    __syncthreads();
    if (k + 1 < nk) loadk((k + 1) << 6);   // in flight during MFMAs below
#pragma unroll
    for (int ks = 0; ks < 2; ks++) {
      bf16x8 af[4], bfr[2];
#pragma unroll
      for (int m = 0; m < 4; m++)
        af[m] = *(const bf16x8*)&As[buf][(wr + m * 16 + l15) * LSTR + ks * 32 + l4 * 8];
#pragma unroll
      for (int n = 0; n < 2; n++)
        bfr[n] = *(const bf16x8*)&Bs[buf][(wc + n * 16 + l15) * LSTR + ks * 32 + l4 * 8];
#pragma unroll
      for (int m = 0; m < 4; m++)
#pragma unroll
        for (int n = 0; n < 2; n++)
          acc[m][n] = __builtin_amdgcn_mfma_f32_16x16x32_bf16(af[m], bfr[n], acc[m][n], 0, 0, 0);
    }
    // no trailing barrier: double-buffered, WAR safe across the single barrier
  }

  // epilogue (C/D layout: col=lane&15, row=(lane>>4)*4+v)
  float* dst = eig + slotOf(b, mode ? 0 : 1);
  double lsum = 0.0; unsigned lcnt = 0;
#pragma unroll
  for (int m = 0; m < 4; m++) {
    int gr = row0 + wr + m * 16 + l4 * 4;
#pragma unroll
    for (int n = 0; n < 2; n++) {
      int gc = col0 + wc + n * 16 + l15;
      float nj = nb[gc];
#pragma unroll
      for (int v = 0; v < 4; v++) {
        int gi = gr + v;
        float d2 = nb[gi] + nj - 2.0f * acc[m][n][v];
        d2 = fmaxf(d2, 0.0f);
        if (gi == gc) d2 = 0.0f;
        if (mode == 0) {
          dst[(size_t)gi * MBS + gc] = d2;
          if (d2 > 0.0f) { lsum += (double)sqrtf(d2); lcnt++; }
        } else {
          dst[(size_t)gi * MBS + gc] = __expf(-d2 * (1.0f / 64.0f)) * (1.0f / 512.0f);
        }
      }
    }
  }
  if (mode == 0) {
    __syncthreads();
    redd[tid] = lsum; redi[tid] = lcnt; __syncthreads();
    for (int o = 256; o > 0; o >>= 1) {
      if (tid < o) { redd[tid] += redd[tid + o]; redi[tid] += redi[tid + o]; }
      __syncthreads();
    }
    if (tid == 0) {
      atomicAdd(&scal[I_SUMD + b], redd[0]);
      atomicAdd(&cnt[b], (unsigned long long)redi[0]);
    }
  }
}

// ---------------- sigma-search sums: 10 sigmas per block ----------------
// grid (16, 5, 8): chunk of 16384 elems, sigma group g (10 sigmas), batch b.
__global__ __launch_bounds__(256) void k_loss(const float* __restrict__ eig,
                                              double* __restrict__ scal,
                                              const unsigned long long* __restrict__ cnt) {
  int b = blockIdx.z, g = blockIdx.y;
  double c = (double)cnt[b]; if (c < 1.0) c = 1.0;
  float md = (float)(scal[I_SUMD + b] / c);
  const float* d2p = eig + slotOf(b, 1);
  const float* ayp = eig + slotOf(b, 2);
  float inv[10];
  double ln[10], ld[10];
#pragma unroll
  for (int i = 0; i < 10; i++) {
    float sg = md * (0.1f + 0.198f * (float)(g * 10 + i));
    inv[i] = 1.0f / (sg * sg);
    ln[i] = 0.0; ld[i] = 0.0;
  }
  size_t base = (size_t)blockIdx.x * 16384 + threadIdx.x;
  for (int l = 0; l < 64; l++) {
    size_t e = base + (size_t)l * 256;
    float d2 = d2p[e];
    float ky = ayp[e] * 512.0f;
#pragma unroll
    for (int i = 0; i < 10; i++) {
      float k = __expf(-d2 * inv[i]);
      ln[i] += (double)(k * ky);
      ld[i] += (double)(k * k);
    }
  }
#pragma unroll
  for (int i = 0; i < 10; i++) {
    double a = ln[i], d = ld[i];
    for (int o = 32; o > 0; o >>= 1) {
      a += __shfl_down(a, o, 64);
      d += __shfl_down(d, o, 64);
    }
    if ((threadIdx.x & 63) == 0) {
      atomicAdd(&scal[I_NUM + b * NSIG + g * 10 + i], a);
      atomicAdd(&scal[I_DEN + b * NSIG + g * 10 + i], d);
    }
  }
}

// ---------------- argmax + EMA sigma chain ----------------
__global__ void k_sigma(double* __restrict__ scal, const unsigned long long* __restrict__ cnt) {
  if (threadIdx.x == 0) {
    double sigma = 0.0;
    for (int b = 0; b < NBATCH; b++) {
      double c = (double)cnt[b]; if (c < 1.0) c = 1.0;
      double md = scal[I_SUMD + b] / c;
      double kyf = sqrt(scal[I_KYF + b]);
      double best = -1.0; int bi = 0;
      for (int s = 0; s < NSIG; s++) {
        double num = scal[I_NUM + b * NSIG + s];
        double den = sqrt(scal[I_DEN + b * NSIG + s]) * kyf;
        double loss = num / den;
        if (loss > best) { best = loss; bi = s; }
      }
      double st = md * (0.1 + 0.198 * (double)bi);
      sigma = (b == 0) ? st : 0.5 * sigma + 0.5 * st;
      scal[I_SIGMA + b] = sigma;
    }
  }
}

// ---------------- A build + Schur products (fused) ----------------
__global__ void k_aj(float* __restrict__ eig, const double* __restrict__ scal) {
  int b = blockIdx.y;
  float sg = (float)scal[I_SIGMA + b];
  float inv = 1.0f / (sg * sg);
  size_t e = (size_t)blockIdx.x * 256 + threadIdx.x;
  float a = __expf(-eig[slotOf(b, 1) + e] * inv) * (1.0f / 512.0f);
  eig[slotOf(b, 1) + e] = a;
  eig[slotOf(b, 3) + e] = eig[slotOf(b, 0) + e] * a;
  eig[slotOf(b, 4) + e] = a * eig[slotOf(b, 2) + e];
}

// ---------------- symmetric eigenvalues (threshold Jacobi) + entropy ----------------
__global__ __launch_bounds__(512) void k_eigen(float* __restrict__ eig, double* __restrict__ scal) {
  int blk = blockIdx.x; int b = blk / 5, m = blk % 5;
  float* M = eig + slotOf(b, m);
  int t = threadIdx.x;
  __shared__ double red[512];
  __shared__ float csA[256], csB[256];
  __shared__ int anyrot;
  __shared__ double sh_scale, sh_off2;

  // trace (of raw matrix; Jacobi preserves it)
  red[t] = (double)M[(size_t)t * 513]; __syncthreads();
  for (int o = 256; o > 0; o >>= 1) { if (t < o) red[t] += red[t + o]; __syncthreads(); }
  if (t == 0) { double trace = red[0]; sh_scale = (m >= 3) ? 1.0 / trace : 1.0; }
  __syncthreads();
  double scale = sh_scale;

  for (int sweep = 0; sweep < 30; sweep++) {
    // off-diagonal Frobenius^2 (column-wise, coalesced)
    double s2 = 0.0;
    for (int i = 0; i < 512; i++) {
      if (i != t) { float v = M[(size_t)i * 512 + t]; s2 += (double)v * v; }
    }
    red[t] = s2; __syncthreads();
    for (int o = 256; o > 0; o >>= 1) { if (t < o) red[t] += red[t + o]; __syncthreads(); }
    if (t == 0) sh_off2 = red[0];
    __syncthreads();
    // entropy error is 2nd-order: ~739*off2 ~ 7e-6 at this threshold
    if (sh_off2 * scale * scale <= 1e-8) break;

    for (int r = 0; r < 511; r++) {
      if (t == 0) anyrot = 0;
      __syncthreads();
      if (t < 256) {
        int p, q;
        if (t == 0) { p = 511; q = r; }
        else { p = (r + t) % 511; q = (r + 511 - t) % 511; }
        float app = M[(size_t)p * 512 + p];
        float aqq = M[(size_t)q * 512 + q];
        float apq = M[(size_t)p * 512 + q];
        float c = 1.0f, sr = 0.0f;
        if (fabsf(apq) > 1e-12f) {
          float th = (aqq - app) / (2.0f * apq);
          float tt = ((th >= 0.0f) ? 1.0f : -1.0f) / (fabsf(th) + sqrtf(1.0f + th * th));
          c = 1.0f / sqrtf(1.0f + tt * tt);
          sr = tt * c;
          anyrot = 1;
        }
        csA[t] = c; csB[t] = sr;
      }
      __syncthreads();
      if (anyrot) {
        int pair = t >> 1, half = t & 1;
        float c = csA[pair], sr = csB[pair];
        int p, q;
        if (pair == 0) { p = 511; q = r; }
        else { p = (r + pair) % 511; q = (r + 511 - pair) % 511; }
        if (sr != 0.0f) {   // rows: J^T A
          size_t rp = (size_t)p * 512, rq = (size_t)q * 512;
          int j0 = half * 256;
          for (int j = j0; j < j0 + 256; j++) {
            float xx = M[rp + j], yy = M[rq + j];
            M[rp + j] = c * xx - sr * yy;
            M[rq + j] = sr * xx + c * yy;
          }
        }
        __syncthreads();
        if (sr != 0.0f) {   // cols: (J^T A) J
          int j0 = half * 256;
          for (int j = j0; j < j0 + 256; j++) {
            float xx = M[(size_t)j * 512 + p], yy = M[(size_t)j * 512 + q];
            M[(size_t)j * 512 + p] = c * xx - sr * yy;
            M[(size_t)j * 512 + q] = sr * xx + c * yy;
          }
        }
      }
      __syncthreads();
    }
  }

  // entropy from (near-)diagonal
  double w = (double)M[(size_t)t * 513] * scale + 1e-6;
  red[t] = -w * log2(w); __syncthreads();
  for (int o = 256; o > 0; o >>= 1) { if (t < o) red[t] += red[t + o]; __syncthreads(); }
  if (t == 0) scal[I_ENT + b * 5 + m] = red[0];
}

// ---------------- finalize MI means ----------------
__global__ void k_final(const double* __restrict__ scal, float* __restrict__ out) {
  if (threadIdx.x == 0) {
    double ixt = 0.0, ity = 0.0;
    for (int b = 0; b < NBATCH; b++) {
      const double* E = &scal[I_ENT + b * 5];
      ixt += E[0] + E[1] - E[3];
      ity += E[1] + E[2] - E[4];
    }
    out[NTOT]     = (float)(ixt / 8.0);
    out[NTOT + 1] = (float)(ity / 8.0);
  }
}

extern "C" void kernel_launch(void* const* d_in, const int* in_sizes, int n_in,
                              void* d_out, int out_size, void* d_ws, size_t ws_size,
                              hipStream_t stream) {
  const float* x   = (const float*)d_in[0];
  const float* inp = (const float*)d_in[1];
  const float* lab = (const float*)d_in[2];
  float* out = (float*)d_out;

  char* ws = (char*)d_ws;
  double* scal = (double*)ws;                                  // 912 doubles
  unsigned long long* cnt = (unsigned long long*)(ws + 7296);  // 8 ull -> 7360
  float* nrmx = (float*)(ws + 7424);                           // 4096 f -> 23808
  float* nrmi = (float*)(ws + 23808);                          // 4096 f -> 40192

  // Matrix scratch: d_ws if it fits (then x-copy is fused & runs first),
  // else first 40MB of d_out (then x-copy runs last).
  const size_t EIG_OFF = 65536;
  const size_t NEED = EIG_OFF + (size_t)40 * NN * sizeof(float);
  bool big = ws_size >= NEED;
  float* eig = big ? (float*)(ws + EIG_OFF) : (float*)d_out;

  hipMemsetAsync(ws, 0, 7424, stream);

  if (big) {
    k_rownorm_copy<<<4096, 256, 0, stream>>>((const float4*)x, (float4*)d_out, nrmx);
  } else {
    k_rownorm<<<4096, 256, 0, stream>>>(x, DXX, nrmx);
  }
  k_rownorm<<<4096, 256, 0, stream>>>(inp, DII, nrmi);
  k_ky<<<dim3(1024, NBATCH), 256, 0, stream>>>(lab, eig, scal);
  k_gemm2<<<dim3(4, 4, 16), 512, 0, stream>>>(x, inp, nrmx, nrmi, eig, scal, cnt);
  k_loss<<<dim3(16, 5, NBATCH), 256, 0, stream>>>(eig, scal, cnt);
  k_sigma<<<1, 64, 0, stream>>>(scal, cnt);
  k_aj<<<dim3(1024, NBATCH), 256, 0, stream>>>(eig, scal);
  k_eigen<<<40, 512, 0, stream>>>(eig, scal);
  k_final<<<1, 64, 0, stream>>>(scal, out);
  if (!big) {
    k_copy<<<2048, 256, 0, stream>>>((const float4*)x, (float4*)d_out, NTOT / 4);
  }
}

// Round 5
// 474.306 us; speedup vs baseline: 10.6922x; 1.3364x over previous
//
#include <hip/hip_runtime.h>
#include <hip/hip_bf16.h>
#include <math.h>

// InformationPlane: per 512-batch -> pdist2 GEMMs (bf16 MFMA, symmetric
// lower-triangle tiles + mirror), sigma search, RBF Grams, 5x symmetric
// 512x512 eigvalsh (fast off2 test + Jacobi fallback), Renyi entropies, MI.
// d_out[0..NTOT) = x copy; d_out[NTOT]=Ixt, d_out[NTOT+1]=Ity.
//
// R5: (1) x/inp pre-converted to bf16 once (fused with row norms) -> GEMM
// reads half the bytes; (2) symmetry: 10 of 16 tiles/batch, mirrored writes,
// x2 weights in fused sums; diag tiles load one panel; (3) XCD-grouped block
// ids (id%8 = batch); (4) k_eigen off2 via coalesced float4 pass.
// Scratch: eig(40MB)+xbf(64MB)+inpbf(24MB) = exactly NTOT*4 bytes of d_out
// (x-copy runs last); if ws_size >= 128.1MB everything sits in d_ws and the
// x-copy is fused into k_prep_x instead.

#define NBATCH 8
#define MBS    512
#define DXX    8192
#define DII    3072
#define NSIG   50
#define NN     262144                 // 512*512
#define NTOT   ((size_t)33554432)     // 4096*8192

// scal (double) indices
#define I_SUMD  0    // 8
#define I_KYF   8    // 8
#define I_SIGMA 24   // 8
#define I_ENT   32   // 40 (b*5+m)
#define I_NUM   96   // 8*50
#define I_DEN   512  // 8*50 -> ends 912

typedef __attribute__((ext_vector_type(8))) short bf16x8;
typedef __attribute__((ext_vector_type(4))) float f32x4;

__device__ __forceinline__ size_t slotOf(int b, int m) {
  return ((size_t)(b * 5 + m)) * (size_t)NN;
}

__device__ __forceinline__ short f2b(float f) {
  __hip_bfloat16 h = __float2bfloat16(f);   // pairs fuse to v_cvt_pk_bf16_f32
  return *(short*)&h;
}

// ---------------- copy x -> out (small-ws path only) ----------------
__global__ void k_copy(const float4* __restrict__ src, float4* __restrict__ dst, size_t n4) {
  size_t i = (size_t)blockIdx.x * blockDim.x + threadIdx.x;
  size_t stride = (size_t)gridDim.x * blockDim.x;
  for (; i < n4; i += stride) dst[i] = src[i];
}

// ---------------- x: norm + bf16 convert (+ optional out-copy) ----------------
template <int COPY>
__global__ void k_prep_x(const float4* __restrict__ src, float4* __restrict__ dst,
                         ushort* __restrict__ xbf, float* __restrict__ nrm) {
  int row = blockIdx.x, t = threadIdx.x;
  const float4* p = src + (size_t)row * 2048;
  bf16x8* o = (bf16x8*)(xbf + (size_t)row * 8192);
  double s = 0.0;
#pragma unroll
  for (int l = 0; l < 4; l++) {
    int i = t + l * 256;                 // ushort8 index 0..1023
    float4 a = p[2 * i], c = p[2 * i + 1];
    if (COPY) { float4* q = dst + (size_t)row * 2048; q[2 * i] = a; q[2 * i + 1] = c; }
    bf16x8 v;
    v[0] = f2b(a.x); v[1] = f2b(a.y); v[2] = f2b(a.z); v[3] = f2b(a.w);
    v[4] = f2b(c.x); v[5] = f2b(c.y); v[6] = f2b(c.z); v[7] = f2b(c.w);
    o[i] = v;
    s += (double)a.x * a.x + (double)a.y * a.y + (double)a.z * a.z + (double)a.w * a.w;
    s += (double)c.x * c.x + (double)c.y * c.y + (double)c.z * c.z + (double)c.w * c.w;
  }
  __shared__ double red[256];
  red[t] = s; __syncthreads();
  for (int o2 = 128; o2 > 0; o2 >>= 1) {
    if (t < o2) red[t] += red[t + o2];
    __syncthreads();
  }
  if (t == 0) nrm[row] = (float)red[0];
}

// ---------------- inp: norm + bf16 convert (block 384 = row of 3072) ----------------
__global__ void k_prep_i(const float* __restrict__ src, ushort* __restrict__ ibf,
                         float* __restrict__ nrm) {
  int row = blockIdx.x, t = threadIdx.x;     // t < 384
  const float4* p = (const float4*)(src + (size_t)row * 3072);
  bf16x8* o = (bf16x8*)(ibf + (size_t)row * 3072);
  float4 a = p[2 * t], c = p[2 * t + 1];
  bf16x8 v;
  v[0] = f2b(a.x); v[1] = f2b(a.y); v[2] = f2b(a.z); v[3] = f2b(a.w);
  v[4] = f2b(c.x); v[5] = f2b(c.y); v[6] = f2b(c.z); v[7] = f2b(c.w);
  o[t] = v;
  double s = (double)a.x * a.x + (double)a.y * a.y + (double)a.z * a.z + (double)a.w * a.w
           + (double)c.x * c.x + (double)c.y * c.y + (double)c.z * c.z + (double)c.w * c.w;
  for (int off = 32; off > 0; off >>= 1) s += __shfl_down(s, off, 64);
  __shared__ double wred[6];
  if ((t & 63) == 0) wred[t >> 6] = s;
  __syncthreads();
  if (t == 0) {
    double tt = 0.0;
#pragma unroll
    for (int w = 0; w < 6; w++) tt += wred[w];
    nrm[row] = (float)tt;
  }
}

// ---------------- label kernel Ky (-> Ay slot), ||Ky||_F^2 ----------------
__global__ void k_ky(const float* __restrict__ lab, float* __restrict__ eig, double* __restrict__ scal) {
  int b = blockIdx.y;
  int e = blockIdx.x * 256 + threadIdx.x;   // grid.x = 1024
  int i = e >> 9, j = e & 511;
  const float* L = lab + (size_t)b * MBS * 10;
  float d2 = 0.0f;
#pragma unroll
  for (int d = 0; d < 10; d++) { float t = L[i * 10 + d] - L[j * 10 + d]; d2 += t * t; }
  float ky = __expf(-d2 * 100.0f);          // sigma = 0.1 -> /0.01
  eig[slotOf(b, 2) + e] = ky * (1.0f / 512.0f);   // Ay = Ky/n
  __shared__ double red[256];
  red[threadIdx.x] = (double)ky * ky; __syncthreads();
  for (int o = 128; o > 0; o >>= 1) {
    if (threadIdx.x < o) red[threadIdx.x] += red[threadIdx.x + o];
    __syncthreads();
  }
  if (threadIdx.x == 0) atomicAdd(&scal[I_KYF + b], red[0]);
}

// ---------------- symmetric bf16-MFMA pdist2 GEMM ----------------
// 160 blocks: id%8 = batch (XCD-grouped), id>>3 = mode*10 + tri-tile.
// mode0: x (D=8192) -> d2 to slot(b,1) + fused sum(sqrt),count (x2 off-diag).
// mode1: inp (D=3072) -> Ax = exp(-d2/64)/512 to slot(b,0).
// 128x128 tile (lower triangle only, mirrored), BK=64, 512 thr (8 waves 2x4).
// Double-buffered LDS + register prefetch; 1 barrier/K-step. Diag tiles load
// only the A panel (B fragments read from As).
#define LSTR 72   // ushorts per LDS row: 144B = 16B-aligned, bank-balanced
__global__ __launch_bounds__(512) void k_gemm2(
    const ushort* __restrict__ xbf, const ushort* __restrict__ inpbf,
    const float* __restrict__ nrmx, const float* __restrict__ nrmi,
    float* __restrict__ eig, double* __restrict__ scal,
    unsigned long long* __restrict__ cnt)
{
  int id = blockIdx.x;
  int b = id & 7;
  int tm = id >> 3;                 // 0..19
  int mode = (tm >= 10) ? 1 : 0;
  int tile = tm - mode * 10;        // 0..9 lower-triangle tile
  int bx = (tile >= 6) ? 3 : (tile >= 3) ? 2 : (tile >= 1) ? 1 : 0;
  int by = tile - ((bx * (bx + 1)) >> 1);
  bool diag = (bx == by);
  int D = mode ? DII : DXX;
  const ushort* src = (mode ? inpbf : xbf) + (size_t)b * MBS * D;
  const float* nb = (mode ? nrmi : nrmx) + b * MBS;
  int row0 = bx * 128, col0 = by * 128;

  __shared__ ushort As[2][128 * LSTR];
  __shared__ ushort Bs[2][128 * LSTR];
  __shared__ double redd[512];
  __shared__ unsigned redi[512];

  int tid = threadIdx.x;
  int lane = tid & 63, w = tid >> 6;
  int wr = (w >> 2) * 64, wc = (w & 3) * 32;
  int l15 = lane & 15, l4 = lane >> 4;

  f32x4 acc[4][2];
#pragma unroll
  for (int m = 0; m < 4; m++)
#pragma unroll
    for (int n = 0; n < 2; n++) {
      acc[m][n][0] = 0.f; acc[m][n][1] = 0.f; acc[m][n][2] = 0.f; acc[m][n][3] = 0.f;
    }

  int rr = tid >> 3;            // 0..63
  int cc = (tid & 7) * 8;       // 0..56

  bf16x8 ra0, ra1, rb0, rb1;
  auto loadk = [&](int k0) {
    ra0 = *(const bf16x8*)&src[(size_t)(row0 + rr) * D + k0 + cc];
    ra1 = *(const bf16x8*)&src[(size_t)(row0 + 64 + rr) * D + k0 + cc];
    if (!diag) {
      rb0 = *(const bf16x8*)&src[(size_t)(col0 + rr) * D + k0 + cc];
      rb1 = *(const bf16x8*)&src[(size_t)(col0 + 64 + rr) * D + k0 + cc];
    }
  };

  loadk(0);
  int nk = D >> 6;
  for (int k = 0; k < nk; k++) {
    int buf = k & 1;
    *(bf16x8*)&As[buf][rr * LSTR + cc] = ra0;
    *(bf16x8*)&As[buf][(64 + rr) * LSTR + cc] = ra1;
    if (!diag) {
      *(bf16x8*)&Bs[buf][rr * LSTR + cc] = rb0;
      *(bf16x8*)&Bs[buf][(64 + rr) * LSTR + cc] = rb1;
    }
    __syncthreads();
    if (k + 1 < nk) loadk((k + 1) << 6);   // in flight during MFMAs below
    const ushort* Bsrc = diag ? As[buf] : Bs[buf];
#pragma unroll
    for (int ks = 0; ks < 2; ks++) {
      bf16x8 af[4], bfr[2];
#pragma unroll
      for (int m = 0; m < 4; m++)
        af[m] = *(const bf16x8*)&As[buf][(wr + m * 16 + l15) * LSTR + ks * 32 + l4 * 8];
#pragma unroll
      for (int n = 0; n < 2; n++)
        bfr[n] = *(const bf16x8*)&Bsrc[(wc + n * 16 + l15) * LSTR + ks * 32 + l4 * 8];
#pragma unroll
      for (int m = 0; m < 4; m++)
#pragma unroll
        for (int n = 0; n < 2; n++)
          acc[m][n] = __builtin_amdgcn_mfma_f32_16x16x32_bf16(af[m], bfr[n], acc[m][n], 0, 0, 0);
    }
    // single barrier per K-step: WAR-safe across alternating buffers
  }

  // epilogue (C/D layout: col=lane&15, row=(lane>>4)*4+v); mirror off-diag
  float* dst = eig + slotOf(b, mode ? 0 : 1);
  double lsum = 0.0; unsigned lcnt = 0;
#pragma unroll
  for (int m = 0; m < 4; m++) {
    int gr = row0 + wr + m * 16 + l4 * 4;
#pragma unroll
    for (int n = 0; n < 2; n++) {
      int gc = col0 + wc + n * 16 + l15;
      float nj = nb[gc];
#pragma unroll
      for (int v = 0; v < 4; v++) {
        int gi = gr + v;
        float d2 = nb[gi] + nj - 2.0f * acc[m][n][v];
        d2 = fmaxf(d2, 0.0f);
        if (gi == gc) d2 = 0.0f;
        float val;
        if (mode == 0) {
          val = d2;
          if (d2 > 0.0f) { lsum += (double)sqrtf(d2); lcnt++; }
        } else {
          val = __expf(-d2 * (1.0f / 64.0f)) * (1.0f / 512.0f);
        }
        dst[(size_t)gi * MBS + gc] = val;
        if (!diag) dst[(size_t)gc * MBS + gi] = val;
      }
    }
  }
  if (mode == 0) {
    if (!diag) { lsum *= 2.0; lcnt *= 2; }
    __syncthreads();
    redd[tid] = lsum; redi[tid] = lcnt; __syncthreads();
    for (int o = 256; o > 0; o >>= 1) {
      if (tid < o) { redd[tid] += redd[tid + o]; redi[tid] += redi[tid + o]; }
      __syncthreads();
    }
    if (tid == 0) {
      atomicAdd(&scal[I_SUMD + b], redd[0]);
      atomicAdd(&cnt[b], (unsigned long long)redi[0]);
    }
  }
}

// ---------------- sigma-search sums: 10 sigmas per block ----------------
__global__ __launch_bounds__(256) void k_loss(const float* __restrict__ eig,
                                              double* __restrict__ scal,
                                              const unsigned long long* __restrict__ cnt) {
  int b = blockIdx.z, g = blockIdx.y;
  double c = (double)cnt[b]; if (c < 1.0) c = 1.0;
  float md = (float)(scal[I_SUMD + b] / c);
  const float* d2p = eig + slotOf(b, 1);
  const float* ayp = eig + slotOf(b, 2);
  float inv[10];
  double ln[10], ld[10];
#pragma unroll
  for (int i = 0; i < 10; i++) {
    float sg = md * (0.1f + 0.198f * (float)(g * 10 + i));
    inv[i] = 1.0f / (sg * sg);
    ln[i] = 0.0; ld[i] = 0.0;
  }
  size_t base = (size_t)blockIdx.x * 16384 + threadIdx.x;
  for (int l = 0; l < 64; l++) {
    size_t e = base + (size_t)l * 256;
    float d2 = d2p[e];
    float ky = ayp[e] * 512.0f;
#pragma unroll
    for (int i = 0; i < 10; i++) {
      float k = __expf(-d2 * inv[i]);
      ln[i] += (double)(k * ky);
      ld[i] += (double)(k * k);
    }
  }
#pragma unroll
  for (int i = 0; i < 10; i++) {
    double a = ln[i], d = ld[i];
    for (int o = 32; o > 0; o >>= 1) {
      a += __shfl_down(a, o, 64);
      d += __shfl_down(d, o, 64);
    }
    if ((threadIdx.x & 63) == 0) {
      atomicAdd(&scal[I_NUM + b * NSIG + g * 10 + i], a);
      atomicAdd(&scal[I_DEN + b * NSIG + g * 10 + i], d);
    }
  }
}

// ---------------- argmax + EMA sigma chain ----------------
__global__ void k_sigma(double* __restrict__ scal, const unsigned long long* __restrict__ cnt) {
  if (threadIdx.x == 0) {
    double sigma = 0.0;
    for (int b = 0; b < NBATCH; b++) {
      double c = (double)cnt[b]; if (c < 1.0) c = 1.0;
      double md = scal[I_SUMD + b] / c;
      double kyf = sqrt(scal[I_KYF + b]);
      double best = -1.0; int bi = 0;
      for (int s = 0; s < NSIG; s++) {
        double num = scal[I_NUM + b * NSIG + s];
        double den = sqrt(scal[I_DEN + b * NSIG + s]) * kyf;
        double loss = num / den;
        if (loss > best) { best = loss; bi = s; }
      }
      double st = md * (0.1 + 0.198 * (double)bi);
      sigma = (b == 0) ? st : 0.5 * sigma + 0.5 * st;
      scal[I_SIGMA + b] = sigma;
    }
  }
}

// ---------------- A build + Schur products (fused) ----------------
__global__ void k_aj(float* __restrict__ eig, const double* __restrict__ scal) {
  int b = blockIdx.y;
  float sg = (float)scal[I_SIGMA + b];
  float inv = 1.0f / (sg * sg);
  size_t e = (size_t)blockIdx.x * 256 + threadIdx.x;
  float a = __expf(-eig[slotOf(b, 1) + e] * inv) * (1.0f / 512.0f);
  eig[slotOf(b, 1) + e] = a;
  eig[slotOf(b, 3) + e] = eig[slotOf(b, 0) + e] * a;
  eig[slotOf(b, 4) + e] = a * eig[slotOf(b, 2) + e];
}

// ---------------- symmetric eigenvalues + entropy ----------------
// Fast path: trace/diag2 + coalesced float4 Frobenius pass -> off2 test.
// Slow path (off2 large): threshold Jacobi sweeps (correct for any input).
__global__ __launch_bounds__(512) void k_eigen(float* __restrict__ eig, double* __restrict__ scal) {
  int blk = blockIdx.x; int b = blk / 5, m = blk % 5;
  float* M = eig + slotOf(b, m);
  int t = threadIdx.x;
  __shared__ double red[512], red2[512];
  __shared__ float csA[256], csB[256];
  __shared__ int anyrot;
  __shared__ double sh_scale, sh_off2;

  double dv = (double)M[(size_t)t * 513];
  red[t] = dv; red2[t] = dv * dv; __syncthreads();
  for (int o = 256; o > 0; o >>= 1) {
    if (t < o) { red[t] += red[t + o]; red2[t] += red2[t + o]; }
    __syncthreads();
  }
  if (t == 0) {
    double trace = red[0];
    sh_scale = (m >= 3) ? 1.0 / trace : 1.0;
  }
  double diag2 = red2[0];
  __syncthreads();
  double scale = sh_scale;

  // total Frobenius^2, coalesced
  const float4* M4 = (const float4*)M;
  double s2 = 0.0;
  for (int i = t; i < 65536; i += 512) {
    float4 v = M4[i];
    s2 += (double)v.x * v.x + (double)v.y * v.y + (double)v.z * v.z + (double)v.w * v.w;
  }
  red[t] = s2; __syncthreads();
  for (int o = 256; o > 0; o >>= 1) { if (t < o) red[t] += red[t + o]; __syncthreads(); }
  double off2 = red[0] - diag2;
  __syncthreads();

  if (off2 * scale * scale > 1e-8) {
    // ---- Jacobi fallback (rare) ----
    for (int sweep = 0; sweep < 30; sweep++) {
      double c2 = 0.0;
      for (int i = 0; i < 512; i++) {
        if (i != t) { float v = M[(size_t)i * 512 + t]; c2 += (double)v * v; }
      }
      red[t] = c2; __syncthreads();
      for (int o = 256; o > 0; o >>= 1) { if (t < o) red[t] += red[t + o]; __syncthreads(); }
      if (t == 0) sh_off2 = red[0];
      __syncthreads();
      if (sh_off2 * scale * scale <= 1e-8) break;

      for (int r = 0; r < 511; r++) {
        if (t == 0) anyrot = 0;
        __syncthreads();
        if (t < 256) {
          int p, q;
          if (t == 0) { p = 511; q = r; }
          else { p = (r + t) % 511; q = (r + 511 - t) % 511; }
          float app = M[(size_t)p * 512 + p];
          float aqq = M[(size_t)q * 512 + q];
          float apq = M[(size_t)p * 512 + q];
          float c = 1.0f, sr = 0.0f;
          if (fabsf(apq) > 1e-12f) {
            float th = (aqq - app) / (2.0f * apq);
            float tt = ((th >= 0.0f) ? 1.0f : -1.0f) / (fabsf(th) + sqrtf(1.0f + th * th));
            c = 1.0f / sqrtf(1.0f + tt * tt);
            sr = tt * c;
            anyrot = 1;
          }
          csA[t] = c; csB[t] = sr;
        }
        __syncthreads();
        if (anyrot) {
          int pair = t >> 1, half = t & 1;
          float c = csA[pair], sr = csB[pair];
          int p, q;
          if (pair == 0) { p = 511; q = r; }
          else { p = (r + pair) % 511; q = (r + 511 - pair) % 511; }
          if (sr != 0.0f) {
            size_t rp = (size_t)p * 512, rq = (size_t)q * 512;
            int j0 = half * 256;
            for (int j = j0; j < j0 + 256; j++) {
              float xx = M[rp + j], yy = M[rq + j];
              M[rp + j] = c * xx - sr * yy;
              M[rq + j] = sr * xx + c * yy;
            }
          }
          __syncthreads();
          if (sr != 0.0f) {
            int j0 = half * 256;
            for (int j = j0; j < j0 + 256; j++) {
              float xx = M[(size_t)j * 512 + p], yy = M[(size_t)j * 512 + q];
              M[(size_t)j * 512 + p] = c * xx - sr * yy;
              M[(size_t)j * 512 + q] = sr * xx + c * yy;
            }
          }
        }
        __syncthreads();
      }
    }
    dv = (double)M[(size_t)t * 513];
  }

  double wv = dv * scale + 1e-6;
  red[t] = -wv * log2(wv); __syncthreads();
  for (int o = 256; o > 0; o >>= 1) { if (t < o) red[t] += red[t + o]; __syncthreads(); }
  if (t == 0) scal[I_ENT + b * 5 + m] = red[0];
}

// ---------------- finalize MI means ----------------
__global__ void k_final(const double* __restrict__ scal, float* __restrict__ out) {
  if (threadIdx.x == 0) {
    double ixt = 0.0, ity = 0.0;
    for (int b = 0; b < NBATCH; b++) {
      const double* E = &scal[I_ENT + b * 5];
      ixt += E[0] + E[1] - E[3];
      ity += E[1] + E[2] - E[4];
    }
    out[NTOT]     = (float)(ixt / 8.0);
    out[NTOT + 1] = (float)(ity / 8.0);
  }
}

extern "C" void kernel_launch(void* const* d_in, const int* in_sizes, int n_in,
                              void* d_out, int out_size, void* d_ws, size_t ws_size,
                              hipStream_t stream) {
  const float* x   = (const float*)d_in[0];
  const float* inp = (const float*)d_in[1];
  const float* lab = (const float*)d_in[2];
  float* out = (float*)d_out;

  char* ws = (char*)d_ws;
  double* scal = (double*)ws;                                  // 912 doubles = 7296 B
  unsigned long long* cnt = (unsigned long long*)(ws + 7296);  // 64 B -> 7360
  float* nrmx = (float*)(ws + 7424);                           // 16 KB -> 23808
  float* nrmi = (float*)(ws + 23808);                          // 16 KB -> 40192

  // Scratch layout: eig(40MB) + xbf(64MB) + inpbf(24MB) = 134217728 B exactly.
  // big path: all in ws (offset 64KB), x-copy fused into k_prep_x (runs first).
  // small path: all in d_out[0..NTOT*4), x-copy runs last.
  const size_t EIG_OFF = 65536;
  bool big = ws_size >= EIG_OFF + 134217728ULL;
  char* base = big ? (ws + EIG_OFF) : (char*)d_out;
  float* eig = (float*)base;
  ushort* xbf = (ushort*)(base + 41943040);       // 40*NN*4
  ushort* inpbf = (ushort*)(base + 109051904);    // +4096*8192*2

  hipMemsetAsync(ws, 0, 7424, stream);

  if (big) k_prep_x<1><<<4096, 256, 0, stream>>>((const float4*)x, (float4*)d_out, xbf, nrmx);
  else     k_prep_x<0><<<4096, 256, 0, stream>>>((const float4*)x, nullptr, xbf, nrmx);
  k_prep_i<<<4096, 384, 0, stream>>>(inp, inpbf, nrmi);
  k_ky<<<dim3(1024, NBATCH), 256, 0, stream>>>(lab, eig, scal);
  k_gemm2<<<160, 512, 0, stream>>>(xbf, inpbf, nrmx, nrmi, eig, scal, cnt);
  k_loss<<<dim3(16, 5, NBATCH), 256, 0, stream>>>(eig, scal, cnt);
  k_sigma<<<1, 64, 0, stream>>>(scal, cnt);
  k_aj<<<dim3(1024, NBATCH), 256, 0, stream>>>(eig, scal);
  k_eigen<<<40, 512, 0, stream>>>(eig, scal);
  k_final<<<1, 64, 0, stream>>>(scal, out);
  if (!big) {
    k_copy<<<2048, 256, 0, stream>>>((const float4*)x, (float4*)d_out, NTOT / 4);
  }
}